// Round 5
// baseline (455.825 us; speedup 1.0000x reference)
//
#include <hip/hip_runtime.h>

using bf16x8 = __attribute__((ext_vector_type(8))) short;
using f32x4  = __attribute__((ext_vector_type(4))) float;
using u16 = unsigned short;
using u32 = unsigned int;

// ---------- helpers ----------
__device__ __forceinline__ u16 f2bf(float f) {          // RNE float->bf16
  u32 u = __float_as_uint(f);
  u += 0x7fffu + ((u >> 16) & 1u);
  return (u16)(u >> 16);
}
__device__ __forceinline__ float bf2f(u16 h) {
  return __uint_as_float(((u32)h) << 16);
}
__device__ __forceinline__ uint4 pack8(const u16* h) {
  uint4 r;
  r.x = (u32)h[0] | ((u32)h[1] << 16);
  r.y = (u32)h[2] | ((u32)h[3] << 16);
  r.z = (u32)h[4] | ((u32)h[5] << 16);
  r.w = (u32)h[6] | ((u32)h[7] << 16);
  return r;
}
__device__ __forceinline__ float gelu_fast(float x) {   // == 0.5x(1+tanh(u)) exactly
  float u2 = 1.5957691216057308f * (x + 0.044715f * x * x * x);  // 2u
  return x / (1.0f + __expf(-u2));
}
__device__ __forceinline__ void gload16(const void* g, void* l) {
  __builtin_amdgcn_global_load_lds(
      (const __attribute__((address_space(1))) void*)g,
      (__attribute__((address_space(3))) void*)l, 16, 0, 0);
}

#define BAR()  do { __builtin_amdgcn_s_barrier(); \
                    __builtin_amdgcn_sched_barrier(0); } while (0)
#define WLG0() do { asm volatile("s_waitcnt lgkmcnt(0)" ::: "memory"); \
                    __builtin_amdgcn_sched_barrier(0); } while (0)
#define VMW(n) do { asm volatile("s_waitcnt vmcnt(" #n ")" ::: "memory"); \
                    __builtin_amdgcn_sched_barrier(0); } while (0)

// ---------- weight transpose: [R,C] f32 -> [C,R] bf16 (hi, optional lo) ----------
__global__ __launch_bounds__(256) void transpose_split_kernel(
    const float* __restrict__ in, u16* __restrict__ outH, u16* __restrict__ outL,
    int R, int C)
{
  __shared__ float t[32][33];
  const int lx = threadIdx.x & 31, ly = threadIdx.x >> 5;
  const int c0 = blockIdx.x << 5, r0 = blockIdx.y << 5;
  for (int i = ly; i < 32; i += 8)
    t[i][lx] = in[(long)(r0 + i) * C + c0 + lx];
  __syncthreads();
  for (int i = ly; i < 32; i += 8) {
    float v = t[lx][i];
    long o = (long)(c0 + i) * R + r0 + lx;
    u16 h = f2bf(v);
    outH[o] = h;
    if (outL) outL[o] = f2bf(v - bf2f(h));
  }
}

// ---------- LayerNorm over rows of 512 f32, out bf16 hi (+ optional lo) ----------
__global__ __launch_bounds__(256) void ln_split_kernel(
    const float* __restrict__ x, const float* __restrict__ gamma,
    const float* __restrict__ beta, u16* __restrict__ outH, u16* __restrict__ outL)
{
  const int row  = (blockIdx.x << 2) + (threadIdx.x >> 6);
  const int lane = threadIdx.x & 63;
  const float* xr = x + (long)row * 512 + lane * 8;
  float v[8];
  *(float4*)&v[0] = *(const float4*)xr;
  *(float4*)&v[4] = *(const float4*)(xr + 4);
  float s = 0.f;
#pragma unroll
  for (int j = 0; j < 8; ++j) s += v[j];
#pragma unroll
  for (int o = 32; o; o >>= 1) s += __shfl_xor(s, o);
  const float mu = s * (1.0f / 512.0f);
  float q = 0.f;
#pragma unroll
  for (int j = 0; j < 8; ++j) { float d = v[j] - mu; q += d * d; }
#pragma unroll
  for (int o = 32; o; o >>= 1) q += __shfl_xor(q, o);
  const float rs = rsqrtf(q * (1.0f / 512.0f) + 1e-5f);
  float gv[8], bv[8];
  *(float4*)&gv[0] = *(const float4*)(gamma + lane * 8);
  *(float4*)&gv[4] = *(const float4*)(gamma + lane * 8 + 4);
  *(float4*)&bv[0] = *(const float4*)(beta + lane * 8);
  *(float4*)&bv[4] = *(const float4*)(beta + lane * 8 + 4);
  u16 hs[8], ls[8];
#pragma unroll
  for (int j = 0; j < 8; ++j) {
    float y = (v[j] - mu) * rs * gv[j] + bv[j];
    hs[j] = f2bf(y);
    ls[j] = f2bf(y - bf2f(hs[j]));
  }
  *(uint4*)(outH + (long)row * 512 + lane * 8) = pack8(hs);
  if (outL) *(uint4*)(outL + (long)row * 512 + lane * 8) = pack8(ls);
}

// ---------- row softmax over 512 f32 -> bf16 ----------
__global__ __launch_bounds__(256) void softmax_kernel(
    const float* __restrict__ scores, u16* __restrict__ attn)
{
  const int row  = (blockIdx.x << 2) + (threadIdx.x >> 6);
  const int lane = threadIdx.x & 63;
  const float* sr = scores + (long)row * 512 + lane * 8;
  float v[8];
  *(float4*)&v[0] = *(const float4*)sr;
  *(float4*)&v[4] = *(const float4*)(sr + 4);
  float m = v[0];
#pragma unroll
  for (int j = 1; j < 8; ++j) m = fmaxf(m, v[j]);
#pragma unroll
  for (int o = 32; o; o >>= 1) m = fmaxf(m, __shfl_xor(m, o));
  float e[8], s = 0.f;
#pragma unroll
  for (int j = 0; j < 8; ++j) { e[j] = __expf(v[j] - m); s += e[j]; }
#pragma unroll
  for (int o = 32; o; o >>= 1) s += __shfl_xor(s, o);
  const float inv = 1.0f / s;
  u16 h[8];
#pragma unroll
  for (int j = 0; j < 8; ++j) h[j] = f2bf(e[j] * inv);
  *(uint4*)(attn + (long)row * 512 + lane * 8) = pack8(h);
}

// ---------- 256x256 8-wave NT GEMM, BK=64 — m201-faithful 4-phase schedule ----
// C[m,n] = sum_k A[m,k]*B[n,k]. K in NT tiles of 64; tile t uses part (t>>3)
// (hi/lo K-concatenation for split-precision GEMMs without materializing).
// LDS 128KB: A regions (d,h) at d*32768+h*16384 (h = M-half, 128 rows x 64K);
//            B regions at +65536 (h = N-half). Row r at r*128B, K-slot s
//            (16B) XOR-swizzled to position s^(r&7).
// Per K-tile, phases split by (m-half mh, k-half kh); 16 MFMA each; B k-half
// fragments (bk0/bk1) are read ONCE (P1/P2) and held in registers -> B's LDS
// region is dead after P2.
//   P1: read A[mh0,kh0](4)+B[kh0](4); stage A(t+1)h0; BAR; lgkm0; MFMA; BAR
//   P2: read A[mh0,kh1](4)+B[kh1](4); stage A(t+1)h1; BAR; lgkm0; MFMA; BAR
//   P3: read A[mh1,kh0](4);           stage B(t+2)h0; BAR; lgkm0; MFMA; BAR
//   P4: read A[mh1,kh1](4);           stage B(t+2)h1; vmcnt(4); BAR; lgkm0;
//                                     MFMA; BAR
// Region safety: A(t+1)->region(d^1) dead since P4(t-1)'s final BAR;
// B(t+2)->region(d) dead after P2(t) (bk in regs). vmcnt(4) per tile forces
// A(t+1) (2-3 phase lead) + B(t+1) (6-phase lead) landed, leaves B(t+2)'s 4
// loads in flight -> queue never drains (T4). Tail: t==NT-2 -> vmcnt(0).
// Two barriers per phase (T3 lockstep); setprio(1) around MFMA (T5);
// XCD-chunked block swizzle (T1); swapped-operand MFMA -> wide stores.
// EPI: 0 bf16 sqrt(v^2+eps); 1 split hi/lo; 2 f32 sqrt(v^2+eps); 3 resid+v;
//      4 gelu(v+bias) bf16; 5 resid+v+bias.
template<int EPI>
__global__ __launch_bounds__(512, 2) void gemm8(
    const char* A0, const char* A1, const char* A2, const char* A3,
    const char* B0, const char* B1, const char* B2, const char* B3,
    int N, int NT, int ldAb, int ldBb,
    long sAb, long sBb, long sC,
    float* __restrict__ outF, u16* __restrict__ outU, u16* __restrict__ outU2,
    const float* __restrict__ resid, const float* __restrict__ bias)
{
  __shared__ __align__(16) char lds[131072];
  const int tid = threadIdx.x;
  const int w = tid >> 6, l = tid & 63;
  const int wm = w >> 2, wn = w & 3;

  // XCD-chunked block swizzle (total %8 == 0 for all our launches)
  const int gx = gridDim.x, gy = gridDim.y;
  int flat = ((int)blockIdx.z * gy + (int)blockIdx.y) * gx + (int)blockIdx.x;
  const int total = gx * gy * (int)gridDim.z;
  flat = (flat & 7) * (total >> 3) + (flat >> 3);
  const int bx = flat % gx;
  int rem = flat / gx;
  const int by = rem % gy, bz = rem / gy;

  const long blockM = (long)by * 256;
  const long blockN = (long)bx * 256;
  const long za = (long)bz * sAb;
  const long zb = (long)bz * sBb;
  const char* a0p = A0 + za; const char* a1p = A1 + za;
  const char* a2p = A2 + za; const char* a3p = A3 + za;
  const char* b0p = B0 + zb; const char* b1p = B1 + zb;
  const char* b2p = B2 + zb; const char* b3p = B3 + zb;

  auto partA = [&](int t) { return t < 8 ? a0p : t < 16 ? a1p : t < 24 ? a2p : a3p; };
  auto partB = [&](int t) { return t < 8 ? b0p : t < 16 ? b1p : t < 24 ? b2p : b3p; };

  // staging: thread tid covers region rows {tid>>3} (g=0) and +64 (g=1);
  // global source slot pre-swizzled: (tid&7)^((tid>>3)&7) so the LDS-linear
  // destination ends up XOR-swizzled.
  const long stgSw = ((tid & 7) ^ ((tid >> 3) & 7)) << 4;
  const long raA = (blockM + (tid >> 3)) * (long)ldAb + stgSw;
  const long raB = (blockN + (tid >> 3)) * (long)ldBb + stgSw;
  auto stageA = [&](int t, int h) {
    const char* s = partA(t) + (((long)(t & 7)) << 7) + raA + (long)h * 128 * ldAb;
    char* dptr = lds + ((t & 1) << 15) + (h << 14) + (tid << 4);
    gload16(s, dptr);
    gload16(s + (long)64 * ldAb, dptr + 8192);
  };
  auto stageB = [&](int t, int h) {
    const char* s = partB(t) + (((long)(t & 7)) << 7) + raB + (long)h * 128 * ldBb;
    char* dptr = lds + 65536 + ((t & 1) << 15) + (h << 14) + (tid << 4);
    gload16(s, dptr);
    gload16(s + (long)64 * ldBb, dptr + 8192);
  };

  f32x4 acc[8][4];
#pragma unroll
  for (int i = 0; i < 8; ++i)
#pragma unroll
    for (int j = 0; j < 4; ++j) acc[i][j] = (f32x4){0.f, 0.f, 0.f, 0.f};

  const int lr = l & 15, kg = l >> 4;
  const int x  = kg ^ (l & 7);
  const int po0 = (lr << 7) + (x << 4);          // kh=0 per-lane byte
  const int po1 = (lr << 7) + ((x ^ 4) << 4);    // kh=1 per-lane byte
  const char* aL = lds + (wm << 14);                                   // + d<<15 + mh<<13 + po + mf<<11
  const char* bL = lds + 65536 + ((wn >> 1) << 14) + ((wn & 1) << 13); // + d<<15 + po + nf<<11

  bf16x8 a[4], bk0[4], bk1[4];
  auto readA = [&](const char* p) {
#pragma unroll
    for (int mf = 0; mf < 4; ++mf) a[mf] = *(const bf16x8*)(p + (mf << 11));
  };
  auto readB = [&](bf16x8* d, const char* p) {
#pragma unroll
    for (int nf = 0; nf < 4; ++nf) d[nf] = *(const bf16x8*)(p + (nf << 11));
  };

#define MFMA16(MH, BK)                                                        \
  do {                                                                        \
    __builtin_amdgcn_s_setprio(1);                                            \
    _Pragma("unroll")                                                         \
    for (int mf = 0; mf < 4; ++mf)                                            \
      _Pragma("unroll")                                                       \
      for (int nf = 0; nf < 4; ++nf)                                          \
        acc[MH * 4 + mf][nf] = __builtin_amdgcn_mfma_f32_16x16x32_bf16(       \
            BK[nf], a[mf], acc[MH * 4 + mf][nf], 0, 0, 0);                    \
    __builtin_amdgcn_s_setprio(0);                                            \
  } while (0)

  // prologue: tile 0's A+B, tile 1's B (A(1) staged during tile 0)
  stageA(0, 0); stageA(0, 1); stageB(0, 0); stageB(0, 1);
  if (NT > 1) { stageB(1, 0); stageB(1, 1); VMW(4); } else { VMW(0); }
  BAR();

  for (int t = 0; t < NT; ++t) {
    const int d = t & 1;
    const char* aD = aL + (d << 15);
    const char* bD = bL + (d << 15);
    // ---- P1: (mh0, kh0)
    readA(aD + po0);
    readB(bk0, bD + po0);
    if (t + 1 < NT) stageA(t + 1, 0);
    BAR(); WLG0();
    MFMA16(0, bk0);
    BAR();
    // ---- P2: (mh0, kh1)
    readA(aD + po1);
    readB(bk1, bD + po1);
    if (t + 1 < NT) stageA(t + 1, 1);
    BAR(); WLG0();
    MFMA16(0, bk1);
    BAR();
    // ---- P3: (mh1, kh0)   [B(t) LDS dead -> stage B(t+2) into region d]
    readA(aD + 8192 + po0);
    if (t + 2 < NT) stageB(t + 2, 0);
    BAR(); WLG0();
    MFMA16(1, bk0);
    BAR();
    // ---- P4: (mh1, kh1)
    readA(aD + 8192 + po1);
    if (t + 2 < NT) stageB(t + 2, 1);
    if (t < NT - 2) { VMW(4); } else if (t == NT - 2) { VMW(0); }
    BAR(); WLG0();
    MFMA16(1, bk1);
    BAR();
  }
#undef MFMA16

  // ---- epilogue (swapped layout): m = ..+lr, n = ..+kg*4+r -> wide stores
  const long cb = (long)bz * sC;
  const int m0 = (int)blockM + wm * 128 + lr;
  const int n0 = (int)blockN + wn * 64 + (kg << 2);
#pragma unroll
  for (int mi = 0; mi < 8; ++mi)
#pragma unroll
    for (int ni = 0; ni < 4; ++ni) {
      const int m = m0 + (mi << 4);
      const int n = n0 + (ni << 4);
      const long idx = cb + (long)m * N + n;
      f32x4 v = acc[mi][ni];
      if (EPI == 0) {
        union { u16 h[4]; uint2 u; } p;
#pragma unroll
        for (int r = 0; r < 4; ++r) p.h[r] = f2bf(sqrtf(v[r] * v[r] + 1e-8f));
        *(uint2*)(outU + idx) = p.u;
      } else if (EPI == 1) {
        union { u16 h[4]; uint2 u; } ph, pl;
#pragma unroll
        for (int r = 0; r < 4; ++r) {
          ph.h[r] = f2bf(v[r]);
          pl.h[r] = f2bf(v[r] - bf2f(ph.h[r]));
        }
        *(uint2*)(outU + idx) = ph.u;
        *(uint2*)(outU2 + idx) = pl.u;
      } else if (EPI == 2) {
        f32x4 o;
#pragma unroll
        for (int r = 0; r < 4; ++r) o[r] = sqrtf(v[r] * v[r] + 1e-8f);
        *(f32x4*)(outF + idx) = o;
      } else if (EPI == 3) {
        f32x4 rd = *(const f32x4*)(resid + idx);
#pragma unroll
        for (int r = 0; r < 4; ++r) rd[r] += v[r];
        *(f32x4*)(outF + idx) = rd;
      } else if (EPI == 4) {
        f32x4 bb = *(const f32x4*)(bias + n);
        union { u16 h[4]; uint2 u; } p;
#pragma unroll
        for (int r = 0; r < 4; ++r) p.h[r] = f2bf(gelu_fast(v[r] + bb[r]));
        *(uint2*)(outU + idx) = p.u;
      } else {
        f32x4 rd = *(const f32x4*)(resid + idx);
        f32x4 bb = *(const f32x4*)(bias + n);
#pragma unroll
        for (int r = 0; r < 4; ++r) rd[r] += v[r] + bb[r];
        *(f32x4*)(outF + idx) = rd;
      }
    }
}

// ---------- launch ----------
extern "C" void kernel_launch(void* const* d_in, const int* in_sizes, int n_in,
                              void* d_out, int out_size, void* d_ws, size_t ws_size,
                              hipStream_t stream)
{
  const float* x   = (const float*)d_in[0];
  const float* g1  = (const float*)d_in[1];
  const float* be1 = (const float*)d_in[2];
  const float* Wv  = (const float*)d_in[3];
  const float* Ww  = (const float*)d_in[4];
  const float* g2  = (const float*)d_in[5];
  const float* be2 = (const float*)d_in[6];
  const float* W1  = (const float*)d_in[7];
  const float* b1  = (const float*)d_in[8];
  const float* W2  = (const float*)d_in[9];
  const float* b2  = (const float*)d_in[10];
  float* out = (float*)d_out;

  char* ws = (char*)d_ws;
  // B=64, T=E=512, H=2048, M=B*T=32768. Lifetimes allow heavy aliasing.
  u16* inp_hi  = (u16*)(ws);                 // [0,32M)   LN1 -> vx-GEMM
  u16* inp_lo  = (u16*)(ws + 33554432);      // [32,64M)  LN1 -> scores
  u16* proj_hi = (u16*)(ws + 67108864);      // [64,96M)  proj -> scores
  u16* proj_lo = (u16*)(ws + 100663296);     // [96,128M) proj -> scores
  float* scores= (float*)(ws + 134217728);   // [128,192M) scores -> softmax
  u16* attn    = proj_hi;                    // alias: written after proj dead
  u16* vx      = proj_lo;                    // alias: vx-GEMM runs post-softmax
  u16* h_in    = inp_hi;                     // alias: written after inp dead
  u16* h_mid   = (u16*)(ws + 33554432);      // [32,160M): all dead by MLP1
  char* wb = ws + 201326592;                 // weights live whole run
  u16* WvT  = (u16*)(wb);
  u16* WwTh = (u16*)(wb + 524288);
  u16* WwTl = (u16*)(wb + 1048576);
  u16* W1T  = (u16*)(wb + 1572864);
  u16* W2T  = (u16*)(wb + 3670016);
  // total ws used: ~207.1 MB

  // weight transposes (f32 -> bf16, K-contiguous for NT GEMM)
  transpose_split_kernel<<<dim3(16, 16), 256, 0, stream>>>(Wv, WvT, nullptr, 512, 512);
  transpose_split_kernel<<<dim3(16, 16), 256, 0, stream>>>(Ww, WwTh, WwTl, 512, 512);
  transpose_split_kernel<<<dim3(64, 16), 256, 0, stream>>>(W1, W1T, nullptr, 512, 2048);
  transpose_split_kernel<<<dim3(16, 64), 256, 0, stream>>>(W2, W2T, nullptr, 2048, 512);

  // LN1: x -> inp hi/lo
  ln_split_kernel<<<8192, 256, 0, stream>>>(x, g1, be1, inp_hi, inp_lo);

  // proj = inp@Ww, split 3-term via K-cat: [ih,il,ih] . [Wh,Wh,Wl], K'=1536
  gemm8<1><<<dim3(2, 128, 1), 512, 0, stream>>>(
      (const char*)inp_hi, (const char*)inp_lo, (const char*)inp_hi, (const char*)inp_hi,
      (const char*)WwTh, (const char*)WwTh, (const char*)WwTl, (const char*)WwTl,
      512, 24, 1024, 1024, 0, 0, 0,
      nullptr, proj_hi, proj_lo, nullptr, nullptr);

  // scores[b,i,j] = sqrt((proj_i . inp_j)^2+eps), split: [ph,ph,pl].[ih,il,ih]
  gemm8<2><<<dim3(2, 2, 64), 512, 0, stream>>>(
      (const char*)proj_hi, (const char*)proj_hi, (const char*)proj_lo, (const char*)proj_lo,
      (const char*)inp_hi, (const char*)inp_lo, (const char*)inp_hi, (const char*)inp_hi,
      512, 24, 1024, 1024, 524288, 524288, 262144,
      scores, nullptr, nullptr, nullptr, nullptr);

  // softmax rows -> attn bf16 (into dead proj_hi)
  softmax_kernel<<<8192, 256, 0, stream>>>(scores, attn);

  // vx = sqrt((inp@Wv)^2+eps) (into dead proj_lo)
  gemm8<0><<<dim3(2, 128, 1), 512, 0, stream>>>(
      (const char*)inp_hi, (const char*)inp_hi, (const char*)inp_hi, (const char*)inp_hi,
      (const char*)WvT, (const char*)WvT, (const char*)WvT, (const char*)WvT,
      512, 8, 1024, 1024, 0, 0, 0,
      nullptr, vx, nullptr, nullptr, nullptr);

  // x1 = x + attn@vx^T -> d_out (batched)
  gemm8<3><<<dim3(2, 2, 64), 512, 0, stream>>>(
      (const char*)attn, (const char*)attn, (const char*)attn, (const char*)attn,
      (const char*)vx, (const char*)vx, (const char*)vx, (const char*)vx,
      512, 8, 1024, 1024, 524288, 524288, 262144,
      out, nullptr, nullptr, x, nullptr);

  // LN2: x1 -> h_in (bf16 hi only)
  ln_split_kernel<<<8192, 256, 0, stream>>>(out, g2, be2, h_in, nullptr);

  // h_mid = gelu(h_in@W1 + b1)
  gemm8<4><<<dim3(8, 128, 1), 512, 0, stream>>>(
      (const char*)h_in, (const char*)h_in, (const char*)h_in, (const char*)h_in,
      (const char*)W1T, (const char*)W1T, (const char*)W1T, (const char*)W1T,
      2048, 8, 1024, 1024, 0, 0, 0,
      nullptr, h_mid, nullptr, nullptr, b1);

  // out = x1 + h_mid@W2 + b2  (K=2048 via 4 contiguous parts)
  gemm8<5><<<dim3(2, 128, 1), 512, 0, stream>>>(
      (const char*)h_mid, (const char*)h_mid + 1024, (const char*)h_mid + 2048, (const char*)h_mid + 3072,
      (const char*)W2T, (const char*)W2T + 1024, (const char*)W2T + 2048, (const char*)W2T + 3072,
      512, 32, 4096, 4096, 0, 0, 0,
      out, nullptr, nullptr, out, b2);
}

// Round 6
// 452.177 us; speedup vs baseline: 1.0081x; 1.0081x over previous
//
#include <hip/hip_runtime.h>

using bf16x8 = __attribute__((ext_vector_type(8))) short;
using f32x4  = __attribute__((ext_vector_type(4))) float;
using u16 = unsigned short;
using u32 = unsigned int;

// ---------- helpers ----------
__device__ __forceinline__ u16 f2bf(float f) {          // RNE float->bf16
  u32 u = __float_as_uint(f);
  u += 0x7fffu + ((u >> 16) & 1u);
  return (u16)(u >> 16);
}
__device__ __forceinline__ float bf2f(u16 h) {
  return __uint_as_float(((u32)h) << 16);
}
__device__ __forceinline__ uint4 pack8(const u16* h) {
  uint4 r;
  r.x = (u32)h[0] | ((u32)h[1] << 16);
  r.y = (u32)h[2] | ((u32)h[3] << 16);
  r.z = (u32)h[4] | ((u32)h[5] << 16);
  r.w = (u32)h[6] | ((u32)h[7] << 16);
  return r;
}
__device__ __forceinline__ float gelu_fast(float x) {   // == 0.5x(1+tanh(u)) exactly
  float u2 = 1.5957691216057308f * (x + 0.044715f * x * x * x);  // 2u
  return x / (1.0f + __expf(-u2));
}
__device__ __forceinline__ void gload16(const void* g, void* l) {
  __builtin_amdgcn_global_load_lds(
      (const __attribute__((address_space(1))) void*)g,
      (__attribute__((address_space(3))) void*)l, 16, 0, 0);
}

// De-pinned sync primitives (NO sched_barrier — m141: order-pinning costs ~43%).
// VMW's "memory" clobber keeps LDS/global ops from crossing; compiler manages
// its own counted lgkmcnt for ds_read->MFMA deps (m97 asm evidence).
#define BAR()  __builtin_amdgcn_s_barrier()
#define VMW0() asm volatile("s_waitcnt vmcnt(0)" ::: "memory")

// ---------- weight transpose: [R,C] f32 -> [C,R] bf16 (hi, optional lo) ----------
__global__ __launch_bounds__(256) void transpose_split_kernel(
    const float* __restrict__ in, u16* __restrict__ outH, u16* __restrict__ outL,
    int R, int C)
{
  __shared__ float t[32][33];
  const int lx = threadIdx.x & 31, ly = threadIdx.x >> 5;
  const int c0 = blockIdx.x << 5, r0 = blockIdx.y << 5;
  for (int i = ly; i < 32; i += 8)
    t[i][lx] = in[(long)(r0 + i) * C + c0 + lx];
  __syncthreads();
  for (int i = ly; i < 32; i += 8) {
    float v = t[lx][i];
    long o = (long)(c0 + i) * R + r0 + lx;
    u16 h = f2bf(v);
    outH[o] = h;
    if (outL) outL[o] = f2bf(v - bf2f(h));
  }
}

// ---------- LayerNorm over rows of 512 f32, out bf16 hi (+ optional lo) ----------
__global__ __launch_bounds__(256) void ln_split_kernel(
    const float* __restrict__ x, const float* __restrict__ gamma,
    const float* __restrict__ beta, u16* __restrict__ outH, u16* __restrict__ outL)
{
  const int row  = (blockIdx.x << 2) + (threadIdx.x >> 6);
  const int lane = threadIdx.x & 63;
  const float* xr = x + (long)row * 512 + lane * 8;
  float v[8];
  *(float4*)&v[0] = *(const float4*)xr;
  *(float4*)&v[4] = *(const float4*)(xr + 4);
  float s = 0.f;
#pragma unroll
  for (int j = 0; j < 8; ++j) s += v[j];
#pragma unroll
  for (int o = 32; o; o >>= 1) s += __shfl_xor(s, o);
  const float mu = s * (1.0f / 512.0f);
  float q = 0.f;
#pragma unroll
  for (int j = 0; j < 8; ++j) { float d = v[j] - mu; q += d * d; }
#pragma unroll
  for (int o = 32; o; o >>= 1) q += __shfl_xor(q, o);
  const float rs = rsqrtf(q * (1.0f / 512.0f) + 1e-5f);
  float gv[8], bv[8];
  *(float4*)&gv[0] = *(const float4*)(gamma + lane * 8);
  *(float4*)&gv[4] = *(const float4*)(gamma + lane * 8 + 4);
  *(float4*)&bv[0] = *(const float4*)(beta + lane * 8);
  *(float4*)&bv[4] = *(const float4*)(beta + lane * 8 + 4);
  u16 hs[8], ls[8];
#pragma unroll
  for (int j = 0; j < 8; ++j) {
    float y = (v[j] - mu) * rs * gv[j] + bv[j];
    hs[j] = f2bf(y);
    ls[j] = f2bf(y - bf2f(hs[j]));
  }
  *(uint4*)(outH + (long)row * 512 + lane * 8) = pack8(hs);
  if (outL) *(uint4*)(outL + (long)row * 512 + lane * 8) = pack8(ls);
}

// ---------- row softmax over 512 f32 -> bf16 ----------
__global__ __launch_bounds__(256) void softmax_kernel(
    const float* __restrict__ scores, u16* __restrict__ attn)
{
  const int row  = (blockIdx.x << 2) + (threadIdx.x >> 6);
  const int lane = threadIdx.x & 63;
  const float* sr = scores + (long)row * 512 + lane * 8;
  float v[8];
  *(float4*)&v[0] = *(const float4*)sr;
  *(float4*)&v[4] = *(const float4*)(sr + 4);
  float m = v[0];
#pragma unroll
  for (int j = 1; j < 8; ++j) m = fmaxf(m, v[j]);
#pragma unroll
  for (int o = 32; o; o >>= 1) m = fmaxf(m, __shfl_xor(m, o));
  float e[8], s = 0.f;
#pragma unroll
  for (int j = 0; j < 8; ++j) { e[j] = __expf(v[j] - m); s += e[j]; }
#pragma unroll
  for (int o = 32; o; o >>= 1) s += __shfl_xor(s, o);
  const float inv = 1.0f / s;
  u16 h[8];
#pragma unroll
  for (int j = 0; j < 8; ++j) h[j] = f2bf(e[j] * inv);
  *(uint4*)(attn + (long)row * 512 + lane * 8) = pack8(h);
}

// ---------- 256x256 8-wave NT GEMM, BK=64 — DE-PINNED single-barrier loop ----
// C[m,n] = sum_k A[m,k]*B[n,k]. K in NT tiles of 64; tile t uses part (t>>3)
// (hi/lo K-concatenation for split-precision GEMMs without materializing).
// LDS 128KB: A regions (d,h) at d*32768+h*16384 (h = M-half, 128 rows x 64K);
//            B regions at +65536 (h = N-half). Row r at r*128B, K-slot s
//            (16B) XOR-swizzled to position s^(r&7).
// Per K-tile: issue the 8 global_load_lds for tile t+1 FIRST (into buffer
// d^1, whose prior content -- tile t-1 -- was fully read before this tile's
// opening barrier), then 24 ds_read_b128 + 64 MFMA in phase order but with
// NO scheduler fences: the compiler software-pipelines reads under MFMAs
// with its own counted lgkmcnt (m97-verified behavior; m141 showed explicit
// sched_barrier(0) pinning costs ~43%). One vmcnt(0)+s_barrier per tile:
// the drain targets loads issued a full tile body (~2.5k cyc) earlier, so
// it is near-free; the barrier publishes the staged buffer across waves.
// XCD-chunked block swizzle (T1); swapped-operand MFMA -> wide stores.
// EPI: 0 bf16 sqrt(v^2+eps); 1 split hi/lo; 2 f32 sqrt(v^2+eps); 3 resid+v;
//      4 gelu(v+bias) bf16; 5 resid+v+bias.
template<int EPI>
__global__ __launch_bounds__(512, 2) void gemm8(
    const char* A0, const char* A1, const char* A2, const char* A3,
    const char* B0, const char* B1, const char* B2, const char* B3,
    int N, int NT, int ldAb, int ldBb,
    long sAb, long sBb, long sC,
    float* __restrict__ outF, u16* __restrict__ outU, u16* __restrict__ outU2,
    const float* __restrict__ resid, const float* __restrict__ bias)
{
  __shared__ __align__(16) char lds[131072];
  const int tid = threadIdx.x;
  const int w = tid >> 6, l = tid & 63;
  const int wm = w >> 2, wn = w & 3;

  // XCD-chunked block swizzle (total %8 == 0 for all our launches)
  const int gx = gridDim.x, gy = gridDim.y;
  int flat = ((int)blockIdx.z * gy + (int)blockIdx.y) * gx + (int)blockIdx.x;
  const int total = gx * gy * (int)gridDim.z;
  flat = (flat & 7) * (total >> 3) + (flat >> 3);
  const int bx = flat % gx;
  int rem = flat / gx;
  const int by = rem % gy, bz = rem / gy;

  const long blockM = (long)by * 256;
  const long blockN = (long)bx * 256;
  const long za = (long)bz * sAb;
  const long zb = (long)bz * sBb;
  const char* a0p = A0 + za; const char* a1p = A1 + za;
  const char* a2p = A2 + za; const char* a3p = A3 + za;
  const char* b0p = B0 + zb; const char* b1p = B1 + zb;
  const char* b2p = B2 + zb; const char* b3p = B3 + zb;

  auto partA = [&](int t) { return t < 8 ? a0p : t < 16 ? a1p : t < 24 ? a2p : a3p; };
  auto partB = [&](int t) { return t < 8 ? b0p : t < 16 ? b1p : t < 24 ? b2p : b3p; };

  // staging: thread tid covers region rows {tid>>3} (g=0) and +64 (g=1);
  // global source slot pre-swizzled: (tid&7)^((tid>>3)&7) so the LDS-linear
  // destination ends up XOR-swizzled.
  const long stgSw = ((tid & 7) ^ ((tid >> 3) & 7)) << 4;
  const long raA = (blockM + (tid >> 3)) * (long)ldAb + stgSw;
  const long raB = (blockN + (tid >> 3)) * (long)ldBb + stgSw;
  auto stageA = [&](int t, int h) {
    const char* s = partA(t) + (((long)(t & 7)) << 7) + raA + (long)h * 128 * ldAb;
    char* dptr = lds + ((t & 1) << 15) + (h << 14) + (tid << 4);
    gload16(s, dptr);
    gload16(s + (long)64 * ldAb, dptr + 8192);
  };
  auto stageB = [&](int t, int h) {
    const char* s = partB(t) + (((long)(t & 7)) << 7) + raB + (long)h * 128 * ldBb;
    char* dptr = lds + 65536 + ((t & 1) << 15) + (h << 14) + (tid << 4);
    gload16(s, dptr);
    gload16(s + (long)64 * ldBb, dptr + 8192);
  };

  f32x4 acc[8][4];
#pragma unroll
  for (int i = 0; i < 8; ++i)
#pragma unroll
    for (int j = 0; j < 4; ++j) acc[i][j] = (f32x4){0.f, 0.f, 0.f, 0.f};

  const int lr = l & 15, kg = l >> 4;
  const int x  = kg ^ (l & 7);
  const int po0 = (lr << 7) + (x << 4);          // kh=0 per-lane byte
  const int po1 = (lr << 7) + ((x ^ 4) << 4);    // kh=1 per-lane byte
  const char* aL = lds + (wm << 14);                                   // + d<<15 + mh*8192 + po + mf<<11
  const char* bL = lds + 65536 + ((wn >> 1) << 14) + ((wn & 1) << 13); // + d<<15 + po + nf<<11

  bf16x8 a[4], bk0[4], bk1[4];
  auto readA = [&](const char* p) {
#pragma unroll
    for (int mf = 0; mf < 4; ++mf) a[mf] = *(const bf16x8*)(p + (mf << 11));
  };
  auto readB = [&](bf16x8* d, const char* p) {
#pragma unroll
    for (int nf = 0; nf < 4; ++nf) d[nf] = *(const bf16x8*)(p + (nf << 11));
  };

#define MFMA16(MH, BK)                                                        \
  do {                                                                        \
    _Pragma("unroll")                                                         \
    for (int mf = 0; mf < 4; ++mf)                                            \
      _Pragma("unroll")                                                       \
      for (int nf = 0; nf < 4; ++nf)                                          \
        acc[MH * 4 + mf][nf] = __builtin_amdgcn_mfma_f32_16x16x32_bf16(       \
            BK[nf], a[mf], acc[MH * 4 + mf][nf], 0, 0, 0);                    \
  } while (0)

  // prologue: stage tile 0, publish
  stageA(0, 0); stageA(0, 1); stageB(0, 0); stageB(0, 1);
  VMW0();
  BAR();

  for (int t = 0; t < NT; ++t) {
    const int d = t & 1;
    const char* aD = aL + (d << 15);
    const char* bD = bL + (d << 15);
    // issue next tile's staging first (into the other buffer; its previous
    // content was fully consumed before this tile's opening barrier)
    if (t + 1 < NT) {
      stageA(t + 1, 0); stageA(t + 1, 1); stageB(t + 1, 0); stageB(t + 1, 1);
    }
    // compute tile t (phase order as a hint; compiler pipelines freely)
    readA(aD + po0);
    readB(bk0, bD + po0);
    MFMA16(0, bk0);
    readA(aD + po1);
    readB(bk1, bD + po1);
    MFMA16(0, bk1);
    readA(aD + 8192 + po0);
    MFMA16(1, bk0);
    readA(aD + 8192 + po1);
    MFMA16(1, bk1);
    if (t + 1 < NT) {
      VMW0();   // staged loads issued a full tile ago -> near-free drain
      BAR();    // publish buffer d^1 across waves
    }
  }
#undef MFMA16

  // ---- epilogue (swapped layout): m = ..+lr, n = ..+kg*4+r -> wide stores
  const long cb = (long)bz * sC;
  const int m0 = (int)blockM + wm * 128 + lr;
  const int n0 = (int)blockN + wn * 64 + (kg << 2);
#pragma unroll
  for (int mi = 0; mi < 8; ++mi)
#pragma unroll
    for (int ni = 0; ni < 4; ++ni) {
      const int m = m0 + (mi << 4);
      const int n = n0 + (ni << 4);
      const long idx = cb + (long)m * N + n;
      f32x4 v = acc[mi][ni];
      if (EPI == 0) {
        union { u16 h[4]; uint2 u; } p;
#pragma unroll
        for (int r = 0; r < 4; ++r) p.h[r] = f2bf(sqrtf(v[r] * v[r] + 1e-8f));
        *(uint2*)(outU + idx) = p.u;
      } else if (EPI == 1) {
        union { u16 h[4]; uint2 u; } ph, pl;
#pragma unroll
        for (int r = 0; r < 4; ++r) {
          ph.h[r] = f2bf(v[r]);
          pl.h[r] = f2bf(v[r] - bf2f(ph.h[r]));
        }
        *(uint2*)(outU + idx) = ph.u;
        *(uint2*)(outU2 + idx) = pl.u;
      } else if (EPI == 2) {
        f32x4 o;
#pragma unroll
        for (int r = 0; r < 4; ++r) o[r] = sqrtf(v[r] * v[r] + 1e-8f);
        *(f32x4*)(outF + idx) = o;
      } else if (EPI == 3) {
        f32x4 rd = *(const f32x4*)(resid + idx);
#pragma unroll
        for (int r = 0; r < 4; ++r) rd[r] += v[r];
        *(f32x4*)(outF + idx) = rd;
      } else if (EPI == 4) {
        f32x4 bb = *(const f32x4*)(bias + n);
        union { u16 h[4]; uint2 u; } p;
#pragma unroll
        for (int r = 0; r < 4; ++r) p.h[r] = f2bf(gelu_fast(v[r] + bb[r]));
        *(uint2*)(outU + idx) = p.u;
      } else {
        f32x4 rd = *(const f32x4*)(resid + idx);
        f32x4 bb = *(const f32x4*)(bias + n);
#pragma unroll
        for (int r = 0; r < 4; ++r) rd[r] += v[r] + bb[r];
        *(f32x4*)(outF + idx) = rd;
      }
    }
}

// ---------- launch ----------
extern "C" void kernel_launch(void* const* d_in, const int* in_sizes, int n_in,
                              void* d_out, int out_size, void* d_ws, size_t ws_size,
                              hipStream_t stream)
{
  const float* x   = (const float*)d_in[0];
  const float* g1  = (const float*)d_in[1];
  const float* be1 = (const float*)d_in[2];
  const float* Wv  = (const float*)d_in[3];
  const float* Ww  = (const float*)d_in[4];
  const float* g2  = (const float*)d_in[5];
  const float* be2 = (const float*)d_in[6];
  const float* W1  = (const float*)d_in[7];
  const float* b1  = (const float*)d_in[8];
  const float* W2  = (const float*)d_in[9];
  const float* b2  = (const float*)d_in[10];
  float* out = (float*)d_out;

  char* ws = (char*)d_ws;
  // B=64, T=E=512, H=2048, M=B*T=32768. Lifetimes allow heavy aliasing.
  u16* inp_hi  = (u16*)(ws);                 // [0,32M)   LN1 -> vx-GEMM
  u16* inp_lo  = (u16*)(ws + 33554432);      // [32,64M)  LN1 -> scores
  u16* proj_hi = (u16*)(ws + 67108864);      // [64,96M)  proj -> scores
  u16* proj_lo = (u16*)(ws + 100663296);     // [96,128M) proj -> scores
  float* scores= (float*)(ws + 134217728);   // [128,192M) scores -> softmax
  u16* attn    = proj_hi;                    // alias: written after proj dead
  u16* vx      = proj_lo;                    // alias: vx-GEMM runs post-softmax
  u16* h_in    = inp_hi;                     // alias: written after inp dead
  u16* h_mid   = (u16*)(ws + 33554432);      // [32,160M): all dead by MLP1
  char* wb = ws + 201326592;                 // weights live whole run
  u16* WvT  = (u16*)(wb);
  u16* WwTh = (u16*)(wb + 524288);
  u16* WwTl = (u16*)(wb + 1048576);
  u16* W1T  = (u16*)(wb + 1572864);
  u16* W2T  = (u16*)(wb + 3670016);
  // total ws used: ~207.1 MB

  // weight transposes (f32 -> bf16, K-contiguous for NT GEMM)
  transpose_split_kernel<<<dim3(16, 16), 256, 0, stream>>>(Wv, WvT, nullptr, 512, 512);
  transpose_split_kernel<<<dim3(16, 16), 256, 0, stream>>>(Ww, WwTh, WwTl, 512, 512);
  transpose_split_kernel<<<dim3(64, 16), 256, 0, stream>>>(W1, W1T, nullptr, 512, 2048);
  transpose_split_kernel<<<dim3(16, 64), 256, 0, stream>>>(W2, W2T, nullptr, 2048, 512);

  // LN1: x -> inp hi/lo
  ln_split_kernel<<<8192, 256, 0, stream>>>(x, g1, be1, inp_hi, inp_lo);

  // proj = inp@Ww, split 3-term via K-cat: [ih,il,ih] . [Wh,Wh,Wl], K'=1536
  gemm8<1><<<dim3(2, 128, 1), 512, 0, stream>>>(
      (const char*)inp_hi, (const char*)inp_lo, (const char*)inp_hi, (const char*)inp_hi,
      (const char*)WwTh, (const char*)WwTh, (const char*)WwTl, (const char*)WwTl,
      512, 24, 1024, 1024, 0, 0, 0,
      nullptr, proj_hi, proj_lo, nullptr, nullptr);

  // scores[b,i,j] = sqrt((proj_i . inp_j)^2+eps), split: [ph,ph,pl].[ih,il,ih]
  gemm8<2><<<dim3(2, 2, 64), 512, 0, stream>>>(
      (const char*)proj_hi, (const char*)proj_hi, (const char*)proj_lo, (const char*)proj_lo,
      (const char*)inp_hi, (const char*)inp_lo, (const char*)inp_hi, (const char*)inp_hi,
      512, 24, 1024, 1024, 524288, 524288, 262144,
      scores, nullptr, nullptr, nullptr, nullptr);

  // softmax rows -> attn bf16 (into dead proj_hi)
  softmax_kernel<<<8192, 256, 0, stream>>>(scores, attn);

  // vx = sqrt((inp@Wv)^2+eps) (into dead proj_lo)
  gemm8<0><<<dim3(2, 128, 1), 512, 0, stream>>>(
      (const char*)inp_hi, (const char*)inp_hi, (const char*)inp_hi, (const char*)inp_hi,
      (const char*)WvT, (const char*)WvT, (const char*)WvT, (const char*)WvT,
      512, 8, 1024, 1024, 0, 0, 0,
      nullptr, vx, nullptr, nullptr, nullptr);

  // x1 = x + attn@vx^T -> d_out (batched)
  gemm8<3><<<dim3(2, 2, 64), 512, 0, stream>>>(
      (const char*)attn, (const char*)attn, (const char*)attn, (const char*)attn,
      (const char*)vx, (const char*)vx, (const char*)vx, (const char*)vx,
      512, 8, 1024, 1024, 524288, 524288, 262144,
      out, nullptr, nullptr, x, nullptr);

  // LN2: x1 -> h_in (bf16 hi only)
  ln_split_kernel<<<8192, 256, 0, stream>>>(out, g2, be2, h_in, nullptr);

  // h_mid = gelu(h_in@W1 + b1)
  gemm8<4><<<dim3(8, 128, 1), 512, 0, stream>>>(
      (const char*)h_in, (const char*)h_in, (const char*)h_in, (const char*)h_in,
      (const char*)W1T, (const char*)W1T, (const char*)W1T, (const char*)W1T,
      2048, 8, 1024, 1024, 0, 0, 0,
      nullptr, h_mid, nullptr, nullptr, b1);

  // out = x1 + h_mid@W2 + b2  (K=2048 via 4 contiguous parts)
  gemm8<5><<<dim3(2, 128, 1), 512, 0, stream>>>(
      (const char*)h_mid, (const char*)h_mid + 1024, (const char*)h_mid + 2048, (const char*)h_mid + 3072,
      (const char*)W2T, (const char*)W2T + 1024, (const char*)W2T + 2048, (const char*)W2T + 3072,
      512, 32, 4096, 4096, 0, 0, 0,
      out, nullptr, nullptr, out, b2);
}

// Round 7
// 443.025 us; speedup vs baseline: 1.0289x; 1.0207x over previous
//
#include <hip/hip_runtime.h>

using bf16x8 = __attribute__((ext_vector_type(8))) short;
using f32x4  = __attribute__((ext_vector_type(4))) float;
using u16 = unsigned short;
using u32 = unsigned int;

// ---------- helpers ----------
__device__ __forceinline__ u16 f2bf(float f) {          // RNE float->bf16
  u32 u = __float_as_uint(f);
  u += 0x7fffu + ((u >> 16) & 1u);
  return (u16)(u >> 16);
}
__device__ __forceinline__ float bf2f(u16 h) {
  return __uint_as_float(((u32)h) << 16);
}
__device__ __forceinline__ uint4 pack8(const u16* h) {
  uint4 r;
  r.x = (u32)h[0] | ((u32)h[1] << 16);
  r.y = (u32)h[2] | ((u32)h[3] << 16);
  r.z = (u32)h[4] | ((u32)h[5] << 16);
  r.w = (u32)h[6] | ((u32)h[7] << 16);
  return r;
}
__device__ __forceinline__ float gelu_fast(float x) {   // == 0.5x(1+tanh(u)) exactly
  float u2 = 1.5957691216057308f * (x + 0.044715f * x * x * x);  // 2u
  return x / (1.0f + __expf(-u2));
}
__device__ __forceinline__ void gload16(const void* g, void* l) {
  __builtin_amdgcn_global_load_lds(
      (const __attribute__((address_space(1))) void*)g,
      (__attribute__((address_space(3))) void*)l, 16, 0, 0);
}

// ---------- weight transpose: [R,C] f32 -> [C,R] bf16 (hi, optional lo) ----------
__global__ __launch_bounds__(256) void transpose_split_kernel(
    const float* __restrict__ in, u16* __restrict__ outH, u16* __restrict__ outL,
    int R, int C)
{
  __shared__ float t[32][33];
  const int lx = threadIdx.x & 31, ly = threadIdx.x >> 5;
  const int c0 = blockIdx.x << 5, r0 = blockIdx.y << 5;
  for (int i = ly; i < 32; i += 8)
    t[i][lx] = in[(long)(r0 + i) * C + c0 + lx];
  __syncthreads();
  for (int i = ly; i < 32; i += 8) {
    float v = t[lx][i];
    long o = (long)(c0 + i) * R + r0 + lx;
    u16 h = f2bf(v);
    outH[o] = h;
    if (outL) outL[o] = f2bf(v - bf2f(h));
  }
}

// ---------- LayerNorm over rows of 512 f32, out bf16 hi (+ optional lo) ----------
__global__ __launch_bounds__(256) void ln_split_kernel(
    const float* __restrict__ x, const float* __restrict__ gamma,
    const float* __restrict__ beta, u16* __restrict__ outH, u16* __restrict__ outL)
{
  const int row  = (blockIdx.x << 2) + (threadIdx.x >> 6);
  const int lane = threadIdx.x & 63;
  const float* xr = x + (long)row * 512 + lane * 8;
  float v[8];
  *(float4*)&v[0] = *(const float4*)xr;
  *(float4*)&v[4] = *(const float4*)(xr + 4);
  float s = 0.f;
#pragma unroll
  for (int j = 0; j < 8; ++j) s += v[j];
#pragma unroll
  for (int o = 32; o; o >>= 1) s += __shfl_xor(s, o);
  const float mu = s * (1.0f / 512.0f);
  float q = 0.f;
#pragma unroll
  for (int j = 0; j < 8; ++j) { float d = v[j] - mu; q += d * d; }
#pragma unroll
  for (int o = 32; o; o >>= 1) q += __shfl_xor(q, o);
  const float rs = rsqrtf(q * (1.0f / 512.0f) + 1e-5f);
  float gv[8], bv[8];
  *(float4*)&gv[0] = *(const float4*)(gamma + lane * 8);
  *(float4*)&gv[4] = *(const float4*)(gamma + lane * 8 + 4);
  *(float4*)&bv[0] = *(const float4*)(beta + lane * 8);
  *(float4*)&bv[4] = *(const float4*)(beta + lane * 8 + 4);
  u16 hs[8], ls[8];
#pragma unroll
  for (int j = 0; j < 8; ++j) {
    float y = (v[j] - mu) * rs * gv[j] + bv[j];
    hs[j] = f2bf(y);
    ls[j] = f2bf(y - bf2f(hs[j]));
  }
  *(uint4*)(outH + (long)row * 512 + lane * 8) = pack8(hs);
  if (outL) *(uint4*)(outL + (long)row * 512 + lane * 8) = pack8(ls);
}

// ---------- row softmax over 512 f32 -> bf16 ----------
__global__ __launch_bounds__(256) void softmax_kernel(
    const float* __restrict__ scores, u16* __restrict__ attn)
{
  const int row  = (blockIdx.x << 2) + (threadIdx.x >> 6);
  const int lane = threadIdx.x & 63;
  const float* sr = scores + (long)row * 512 + lane * 8;
  float v[8];
  *(float4*)&v[0] = *(const float4*)sr;
  *(float4*)&v[4] = *(const float4*)(sr + 4);
  float m = v[0];
#pragma unroll
  for (int j = 1; j < 8; ++j) m = fmaxf(m, v[j]);
#pragma unroll
  for (int o = 32; o; o >>= 1) m = fmaxf(m, __shfl_xor(m, o));
  float e[8], s = 0.f;
#pragma unroll
  for (int j = 0; j < 8; ++j) { e[j] = __expf(v[j] - m); s += e[j]; }
#pragma unroll
  for (int o = 32; o; o >>= 1) s += __shfl_xor(s, o);
  const float inv = 1.0f / s;
  u16 h[8];
#pragma unroll
  for (int j = 0; j < 8; ++j) h[j] = f2bf(e[j] * inv);
  *(uint4*)(attn + (long)row * 512 + lane * 8) = pack8(h);
}

// ---------- 256x256 8-wave NT GEMM, BK=64 — NO inline asm, NO reg cap ----------
// C[m,n] = sum_k A[m,k]*B[n,k]. K in NT tiles of 64; tile t uses part (t>>3)
// (hi/lo K-concatenation for split-precision GEMMs without materializing).
// LDS 128KB: A regions (d,h) at d*32768+h*16384 (h = M-half, 128 rows x 64K);
//            B regions at +65536 (h = N-half). Row r at r*128B, K-slot s
//            (16B) XOR-swizzled to position s^(r&7).
// Loop: issue tile t+1's 8 global_load_lds into buffer d^1 (its prior
// content, tile t-1, was fully read before the barrier that opened tile t),
// then 24 ds_read_b128 + 64 MFMA, then ONE __syncthreads() (native
// vmcnt(0)+lgkmcnt(0)+s_barrier) to drain+publish. No inline asm anywhere
// in this kernel (A/B test vs r6: "memory"-clobbered waits + tight
// launch_bounds suspected of causing per-MFMA accvgpr copy churn — the
// VALUBusy ~2x MfmaUtil signature). __launch_bounds__(512) only: occupancy
// is LDS-capped at 1 block/CU regardless, so give the allocator slack.
// XCD-chunked block swizzle (T1); swapped-operand MFMA -> wide stores.
// EPI: 0 bf16 sqrt(v^2+eps); 1 split hi/lo; 2 f32 sqrt(v^2+eps); 3 resid+v;
//      4 gelu(v+bias) bf16; 5 resid+v+bias.
template<int EPI>
__global__ __launch_bounds__(512) void gemm8(
    const char* A0, const char* A1, const char* A2, const char* A3,
    const char* B0, const char* B1, const char* B2, const char* B3,
    int N, int NT, int ldAb, int ldBb,
    long sAb, long sBb, long sC,
    float* __restrict__ outF, u16* __restrict__ outU, u16* __restrict__ outU2,
    const float* __restrict__ resid, const float* __restrict__ bias)
{
  __shared__ __align__(16) char lds[131072];
  const int tid = threadIdx.x;
  const int w = tid >> 6, l = tid & 63;
  const int wm = w >> 2, wn = w & 3;

  // XCD-chunked block swizzle (total %8 == 0 for all our launches)
  const int gx = gridDim.x, gy = gridDim.y;
  int flat = ((int)blockIdx.z * gy + (int)blockIdx.y) * gx + (int)blockIdx.x;
  const int total = gx * gy * (int)gridDim.z;
  flat = (flat & 7) * (total >> 3) + (flat >> 3);
  const int bx = flat % gx;
  int rem = flat / gx;
  const int by = rem % gy, bz = rem / gy;

  const long blockM = (long)by * 256;
  const long blockN = (long)bx * 256;
  const long za = (long)bz * sAb;
  const long zb = (long)bz * sBb;
  const char* a0p = A0 + za; const char* a1p = A1 + za;
  const char* a2p = A2 + za; const char* a3p = A3 + za;
  const char* b0p = B0 + zb; const char* b1p = B1 + zb;
  const char* b2p = B2 + zb; const char* b3p = B3 + zb;

  auto partA = [&](int t) { return t < 8 ? a0p : t < 16 ? a1p : t < 24 ? a2p : a3p; };
  auto partB = [&](int t) { return t < 8 ? b0p : t < 16 ? b1p : t < 24 ? b2p : b3p; };

  // staging: thread tid covers region rows {tid>>3} (g=0) and +64 (g=1);
  // global source slot pre-swizzled: (tid&7)^((tid>>3)&7) so the LDS-linear
  // destination ends up XOR-swizzled.
  const long stgSw = ((tid & 7) ^ ((tid >> 3) & 7)) << 4;
  const long raA = (blockM + (tid >> 3)) * (long)ldAb + stgSw;
  const long raB = (blockN + (tid >> 3)) * (long)ldBb + stgSw;
  auto stageA = [&](int t, int h) {
    const char* s = partA(t) + (((long)(t & 7)) << 7) + raA + (long)h * 128 * ldAb;
    char* dptr = lds + ((t & 1) << 15) + (h << 14) + (tid << 4);
    gload16(s, dptr);
    gload16(s + (long)64 * ldAb, dptr + 8192);
  };
  auto stageB = [&](int t, int h) {
    const char* s = partB(t) + (((long)(t & 7)) << 7) + raB + (long)h * 128 * ldBb;
    char* dptr = lds + 65536 + ((t & 1) << 15) + (h << 14) + (tid << 4);
    gload16(s, dptr);
    gload16(s + (long)64 * ldBb, dptr + 8192);
  };

  f32x4 acc[8][4];
#pragma unroll
  for (int i = 0; i < 8; ++i)
#pragma unroll
    for (int j = 0; j < 4; ++j) acc[i][j] = (f32x4){0.f, 0.f, 0.f, 0.f};

  const int lr = l & 15, kg = l >> 4;
  const int xs = kg ^ (l & 7);
  const int po0 = (lr << 7) + (xs << 4);          // kh=0 per-lane byte
  const int po1 = (lr << 7) + ((xs ^ 4) << 4);    // kh=1 per-lane byte
  const char* aL = lds + (wm << 14);                                   // + d<<15 + mh*8192 + po + mf<<11
  const char* bL = lds + 65536 + ((wn >> 1) << 14) + ((wn & 1) << 13); // + d<<15 + po + nf<<11

  bf16x8 a[4], bk0[4], bk1[4];
  auto readA = [&](const char* p) {
#pragma unroll
    for (int mf = 0; mf < 4; ++mf) a[mf] = *(const bf16x8*)(p + (mf << 11));
  };
  auto readB = [&](bf16x8* d, const char* p) {
#pragma unroll
    for (int nf = 0; nf < 4; ++nf) d[nf] = *(const bf16x8*)(p + (nf << 11));
  };

#define MFMA16(MH, BK)                                                        \
  do {                                                                        \
    _Pragma("unroll")                                                         \
    for (int mf = 0; mf < 4; ++mf)                                            \
      _Pragma("unroll")                                                       \
      for (int nf = 0; nf < 4; ++nf)                                          \
        acc[MH * 4 + mf][nf] = __builtin_amdgcn_mfma_f32_16x16x32_bf16(       \
            BK[nf], a[mf], acc[MH * 4 + mf][nf], 0, 0, 0);                    \
  } while (0)

  // prologue: stage tile 0, publish
  stageA(0, 0); stageA(0, 1); stageB(0, 0); stageB(0, 1);
  __syncthreads();

  for (int t = 0; t < NT; ++t) {
    const int d = t & 1;
    const char* aD = aL + (d << 15);
    const char* bD = bL + (d << 15);
    // issue next tile's staging first (into the other buffer; its previous
    // content was fully consumed before this tile's opening barrier)
    if (t + 1 < NT) {
      stageA(t + 1, 0); stageA(t + 1, 1); stageB(t + 1, 0); stageB(t + 1, 1);
    }
    // compute tile t (phase order as a hint; compiler pipelines freely)
    readA(aD + po0);
    readB(bk0, bD + po0);
    MFMA16(0, bk0);
    readA(aD + po1);
    readB(bk1, bD + po1);
    MFMA16(0, bk1);
    readA(aD + 8192 + po0);
    MFMA16(1, bk0);
    readA(aD + 8192 + po1);
    MFMA16(1, bk1);
    if (t + 1 < NT) __syncthreads();   // drain own loads (issued a full tile
                                       // ago) + publish buffer d^1
  }
#undef MFMA16

  // ---- epilogue (swapped layout): m = ..+lr, n = ..+kg*4+r -> wide stores
  const long cb = (long)bz * sC;
  const int m0 = (int)blockM + wm * 128 + lr;
  const int n0 = (int)blockN + wn * 64 + (kg << 2);
#pragma unroll
  for (int mi = 0; mi < 8; ++mi)
#pragma unroll
    for (int ni = 0; ni < 4; ++ni) {
      const int m = m0 + (mi << 4);
      const int n = n0 + (ni << 4);
      const long idx = cb + (long)m * N + n;
      f32x4 v = acc[mi][ni];
      if (EPI == 0) {
        union { u16 h[4]; uint2 u; } p;
#pragma unroll
        for (int r = 0; r < 4; ++r) p.h[r] = f2bf(sqrtf(v[r] * v[r] + 1e-8f));
        *(uint2*)(outU + idx) = p.u;
      } else if (EPI == 1) {
        union { u16 h[4]; uint2 u; } ph, pl;
#pragma unroll
        for (int r = 0; r < 4; ++r) {
          ph.h[r] = f2bf(v[r]);
          pl.h[r] = f2bf(v[r] - bf2f(ph.h[r]));
        }
        *(uint2*)(outU + idx) = ph.u;
        *(uint2*)(outU2 + idx) = pl.u;
      } else if (EPI == 2) {
        f32x4 o;
#pragma unroll
        for (int r = 0; r < 4; ++r) o[r] = sqrtf(v[r] * v[r] + 1e-8f);
        *(f32x4*)(outF + idx) = o;
      } else if (EPI == 3) {
        f32x4 rd = *(const f32x4*)(resid + idx);
#pragma unroll
        for (int r = 0; r < 4; ++r) rd[r] += v[r];
        *(f32x4*)(outF + idx) = rd;
      } else if (EPI == 4) {
        f32x4 bb = *(const f32x4*)(bias + n);
        union { u16 h[4]; uint2 u; } p;
#pragma unroll
        for (int r = 0; r < 4; ++r) p.h[r] = f2bf(gelu_fast(v[r] + bb[r]));
        *(uint2*)(outU + idx) = p.u;
      } else {
        f32x4 rd = *(const f32x4*)(resid + idx);
        f32x4 bb = *(const f32x4*)(bias + n);
#pragma unroll
        for (int r = 0; r < 4; ++r) rd[r] += v[r] + bb[r];
        *(f32x4*)(outF + idx) = rd;
      }
    }
}

// ---------- launch ----------
extern "C" void kernel_launch(void* const* d_in, const int* in_sizes, int n_in,
                              void* d_out, int out_size, void* d_ws, size_t ws_size,
                              hipStream_t stream)
{
  const float* x   = (const float*)d_in[0];
  const float* g1  = (const float*)d_in[1];
  const float* be1 = (const float*)d_in[2];
  const float* Wv  = (const float*)d_in[3];
  const float* Ww  = (const float*)d_in[4];
  const float* g2  = (const float*)d_in[5];
  const float* be2 = (const float*)d_in[6];
  const float* W1  = (const float*)d_in[7];
  const float* b1  = (const float*)d_in[8];
  const float* W2  = (const float*)d_in[9];
  const float* b2  = (const float*)d_in[10];
  float* out = (float*)d_out;

  char* ws = (char*)d_ws;
  // B=64, T=E=512, H=2048, M=B*T=32768. Lifetimes allow heavy aliasing.
  u16* inp_hi  = (u16*)(ws);                 // [0,32M)   LN1 -> vx-GEMM
  u16* inp_lo  = (u16*)(ws + 33554432);      // [32,64M)  LN1 -> scores
  u16* proj_hi = (u16*)(ws + 67108864);      // [64,96M)  proj -> scores
  u16* proj_lo = (u16*)(ws + 100663296);     // [96,128M) proj -> scores
  float* scores= (float*)(ws + 134217728);   // [128,192M) scores -> softmax
  u16* attn    = proj_hi;                    // alias: written after proj dead
  u16* vx      = proj_lo;                    // alias: vx-GEMM runs post-softmax
  u16* h_in    = inp_hi;                     // alias: written after inp dead
  u16* h_mid   = (u16*)(ws + 33554432);      // [32,160M): all dead by MLP1
  char* wb = ws + 201326592;                 // weights live whole run
  u16* WvT  = (u16*)(wb);
  u16* WwTh = (u16*)(wb + 524288);
  u16* WwTl = (u16*)(wb + 1048576);
  u16* W1T  = (u16*)(wb + 1572864);
  u16* W2T  = (u16*)(wb + 3670016);
  // total ws used: ~207.1 MB

  // weight transposes (f32 -> bf16, K-contiguous for NT GEMM)
  transpose_split_kernel<<<dim3(16, 16), 256, 0, stream>>>(Wv, WvT, nullptr, 512, 512);
  transpose_split_kernel<<<dim3(16, 16), 256, 0, stream>>>(Ww, WwTh, WwTl, 512, 512);
  transpose_split_kernel<<<dim3(64, 16), 256, 0, stream>>>(W1, W1T, nullptr, 512, 2048);
  transpose_split_kernel<<<dim3(16, 64), 256, 0, stream>>>(W2, W2T, nullptr, 2048, 512);

  // LN1: x -> inp hi/lo
  ln_split_kernel<<<8192, 256, 0, stream>>>(x, g1, be1, inp_hi, inp_lo);

  // proj = inp@Ww, split 3-term via K-cat: [ih,il,ih] . [Wh,Wh,Wl], K'=1536
  gemm8<1><<<dim3(2, 128, 1), 512, 0, stream>>>(
      (const char*)inp_hi, (const char*)inp_lo, (const char*)inp_hi, (const char*)inp_hi,
      (const char*)WwTh, (const char*)WwTh, (const char*)WwTl, (const char*)WwTl,
      512, 24, 1024, 1024, 0, 0, 0,
      nullptr, proj_hi, proj_lo, nullptr, nullptr);

  // scores[b,i,j] = sqrt((proj_i . inp_j)^2+eps), split: [ph,ph,pl].[ih,il,ih]
  gemm8<2><<<dim3(2, 2, 64), 512, 0, stream>>>(
      (const char*)proj_hi, (const char*)proj_hi, (const char*)proj_lo, (const char*)proj_lo,
      (const char*)inp_hi, (const char*)inp_lo, (const char*)inp_hi, (const char*)inp_hi,
      512, 24, 1024, 1024, 524288, 524288, 262144,
      scores, nullptr, nullptr, nullptr, nullptr);

  // softmax rows -> attn bf16 (into dead proj_hi)
  softmax_kernel<<<8192, 256, 0, stream>>>(scores, attn);

  // vx = sqrt((inp@Wv)^2+eps) (into dead proj_lo)
  gemm8<0><<<dim3(2, 128, 1), 512, 0, stream>>>(
      (const char*)inp_hi, (const char*)inp_hi, (const char*)inp_hi, (const char*)inp_hi,
      (const char*)WvT, (const char*)WvT, (const char*)WvT, (const char*)WvT,
      512, 8, 1024, 1024, 0, 0, 0,
      nullptr, vx, nullptr, nullptr, nullptr);

  // x1 = x + attn@vx^T -> d_out (batched)
  gemm8<3><<<dim3(2, 2, 64), 512, 0, stream>>>(
      (const char*)attn, (const char*)attn, (const char*)attn, (const char*)attn,
      (const char*)vx, (const char*)vx, (const char*)vx, (const char*)vx,
      512, 8, 1024, 1024, 524288, 524288, 262144,
      out, nullptr, nullptr, x, nullptr);

  // LN2: x1 -> h_in (bf16 hi only)
  ln_split_kernel<<<8192, 256, 0, stream>>>(out, g2, be2, h_in, nullptr);

  // h_mid = gelu(h_in@W1 + b1)
  gemm8<4><<<dim3(8, 128, 1), 512, 0, stream>>>(
      (const char*)h_in, (const char*)h_in, (const char*)h_in, (const char*)h_in,
      (const char*)W1T, (const char*)W1T, (const char*)W1T, (const char*)W1T,
      2048, 8, 1024, 1024, 0, 0, 0,
      nullptr, h_mid, nullptr, nullptr, b1);

  // out = x1 + h_mid@W2 + b2  (K=2048 via 4 contiguous parts)
  gemm8<5><<<dim3(2, 128, 1), 512, 0, stream>>>(
      (const char*)h_mid, (const char*)h_mid + 1024, (const char*)h_mid + 2048, (const char*)h_mid + 3072,
      (const char*)W2T, (const char*)W2T + 1024, (const char*)W2T + 2048, (const char*)W2T + 3072,
      512, 32, 4096, 4096, 0, 0, 0,
      out, nullptr, nullptr, out, b2);
}